// Round 4
// baseline (238.258 us; speedup 1.0000x reference)
//
#include <hip/hip_runtime.h>
#include <hip/hip_bf16.h>
#include <cmath>

// Problem constants
#define BATCH   4096
#define NUNITS  1024
#define INSIZE  512
#define SIGSZ   6
#define KSIG    (NUNITS * SIGSZ)          // 6144
#define SAVED   (KSIG + NUNITS)           // 7168
#define KTOT    (INSIZE + KSIG + NUNITS)  // 7680
#define OUTW    (NUNITS * (SIGSZ + 1))    // 7168

// Workspace layout (ushort elements)
#define WS_AX 0LL
#define WS_AS 2097152LL
#define WS_AT 27262976LL
#define WS_BW 31457280LL
#define WS_BU 31981568LL
#define WS_ELEMS 39321600LL
#define WS_BYTES (WS_ELEMS * 2)           // 78,643,200

typedef __attribute__((ext_vector_type(8))) short bf16x8;
typedef __attribute__((ext_vector_type(8))) unsigned short u16x8;
typedef __attribute__((ext_vector_type(4))) float f32x4;

__device__ __forceinline__ unsigned short f2bf(float f) {
    union { float f; unsigned int u; } c; c.f = f;
    unsigned int u = c.u;
    return (unsigned short)((u + 0x7FFFu + ((u >> 16) & 1u)) >> 16);  // RNE
}

// XOR-swizzled LDS index (ushort units), 128B (64 bf16) rows.
__device__ __forceinline__ int swz(int row, int bytecol) {
    return row * 64 + (((bytecol) ^ ((row & 7) << 4)) >> 1);
}

// ---------------- prepass: fp32 -> packed bf16 in ws ----------------
__global__ __launch_bounds__(256)
void prepack(const float* __restrict__ x, const float* __restrict__ sigs,
             const float* __restrict__ states, const float* __restrict__ Ww,
             const float* __restrict__ Uw, unsigned short* __restrict__ ws)
{
    const long long stride = (long long)gridDim.x * blockDim.x;
    for (long long p = (long long)blockIdx.x * blockDim.x + threadIdx.x;
         p < 4915200LL; p += stride) {
        const float* src; unsigned short* dst; long long o;
        if (p < 262144LL)       { src = x;      dst = ws + WS_AX; o = p; }
        else if (p < 3407872LL) { src = sigs;   dst = ws + WS_AS; o = p - 262144LL; }
        else if (p < 3932160LL) { src = states; dst = ws + WS_AT; o = p - 3407872LL; }
        else if (p < 3997696LL) { src = Ww;     dst = ws + WS_BW; o = p - 3932160LL; }
        else                    { src = Uw;     dst = ws + WS_BU; o = p - 3997696LL; }
        const float4 v0 = *(const float4*)(src + o * 8);
        const float4 v1 = *(const float4*)(src + o * 8 + 4);
        u16x8 h;
        h[0] = f2bf(v0.x); h[1] = f2bf(v0.y); h[2] = f2bf(v0.z); h[3] = f2bf(v0.w);
        h[4] = f2bf(v1.x); h[5] = f2bf(v1.y); h[6] = f2bf(v1.z); h[7] = f2bf(v1.w);
        *(u16x8*)(dst + o * 8) = h;
    }
}

// ---------------- main GEMM + fused sigjoin ----------------
// 128x64 tile, BK=64, 512 threads (8 waves, 4x2 grid of 32x32 wave tiles),
// grid 512 = 2 blocks/CU. Staging via global_load_lds (16B), pre-swizzled source.
#define GLD_LDS(G, L) __builtin_amdgcn_global_load_lds(                        \
        (const __attribute__((address_space(1))) unsigned int*)(G),           \
        (__attribute__((address_space(3))) unsigned int*)(L), 16, 0, 0)

__global__ __launch_bounds__(512, 4)
void rsig_gemm(const unsigned short* __restrict__ ws,
               const float* __restrict__ sigs,
               const float* __restrict__ states,
               const float* __restrict__ Wb,
               const float* __restrict__ Ub,
               const float* __restrict__ lt,
               float* __restrict__ out)
{
    __shared__ unsigned short lA[2][128 * 64];  // 32 KB
    __shared__ unsigned short lB[2][64 * 64];   // 16 KB

    const int t = threadIdx.x;
    // XCD chunk swizzle: 512 blocks, 64/XCD, bm-major chunks (4 bm x 16 bn).
    const int p   = blockIdx.x;
    const int lid = (p & 7) * 64 + (p >> 3);
    const int bm  = lid >> 4;   // 0..31
    const int bn  = lid & 15;   // 0..15

    const int lane = t & 63;
    const int w    = t >> 6;    // 0..7
    const int wm   = w >> 1;    // 4x2 wave grid; wave tile 32x32
    const int wn   = w & 1;
    const int lr   = lane & 15;
    const int lg   = lane >> 4;

    const unsigned short* wsAx = ws + WS_AX;
    const unsigned short* wsAs = ws + WS_AS;
    const unsigned short* wsAt = ws + WS_AT;
    const unsigned short* wsBw = ws + WS_BW;
    const unsigned short* wsBu = ws + WS_BU;

    // pre-swizzled source column (elems) + row-in-group for staging
    const int sCol = 8 * ((lane & 7) ^ (lane >> 3));
    const int sRow = lane >> 3;

    f32x4 acc[2][2];
#pragma unroll
    for (int m = 0; m < 2; ++m)
#pragma unroll
        for (int n = 0; n < 2; ++n)
            acc[m][n] = (f32x4)0.f;

#define STAGE(BUF, KT)                                                                  \
    {                                                                                   \
        const int kt_ = (KT);                                                           \
        const unsigned short* abase; int astr, koff;                                    \
        if (kt_ < 8)        { abase = wsAx; astr = INSIZE; koff = kt_ * 64; }           \
        else if (kt_ < 104) { abase = wsAs; astr = KSIG;   koff = kt_ * 64 - 512; }     \
        else                { abase = wsAt; astr = NUNITS; koff = kt_ * 64 - 6656; }    \
        const unsigned short* bbase; int bstr, koffb;                                   \
        if (kt_ < 8)        { bbase = wsBw; bstr = INSIZE; koffb = kt_ * 64; }          \
        else                { bbase = wsBu; bstr = SAVED;  koffb = kt_ * 64 - 512; }    \
        _Pragma("unroll")                                                               \
        for (int j = 0; j < 2; ++j) {                                                   \
            const int rg = w * 2 + j;  /* 8-row group 0..15 */                          \
            const unsigned short* g = abase                                             \
                + (size_t)(bm * 128 + rg * 8 + sRow) * astr + koff + sCol;              \
            GLD_LDS(g, &lA[BUF][rg * 512]);                                             \
        }                                                                               \
        {                                                                               \
            const unsigned short* g = bbase                                             \
                + (size_t)(bn * 64 + w * 8 + sRow) * bstr + koffb + sCol;               \
            GLD_LDS(g, &lB[BUF][w * 512]);                                              \
        }                                                                               \
    }

    // Prologue
    STAGE(0, 0);
    __syncthreads();   // compiler emits vmcnt(0) before s_barrier

    int c = 0;
    for (int kt = 0; kt < KTOT / 64; ++kt) {
        if (kt + 1 < KTOT / 64) STAGE(c ^ 1, kt + 1);   // DMA in flight over MFMA

#pragma unroll
        for (int ks = 0; ks < 2; ++ks) {
            bf16x8 af[2], bfr[2];
#pragma unroll
            for (int m = 0; m < 2; ++m)
                af[m] = *(const bf16x8*)&lA[c][swz(wm * 32 + m * 16 + lr, ks * 64 + lg * 16)];
#pragma unroll
            for (int n = 0; n < 2; ++n)
                bfr[n] = *(const bf16x8*)&lB[c][swz(wn * 32 + n * 16 + lr, ks * 64 + lg * 16)];
#pragma unroll
            for (int m = 0; m < 2; ++m)
#pragma unroll
                for (int n = 0; n < 2; ++n)
                    acc[m][n] = __builtin_amdgcn_mfma_f32_16x16x32_bf16(af[m], bfr[n], acc[m][n], 0, 0, 0);
        }

        __syncthreads();
        c ^= 1;
    }

    // Epilogue: raw = acc + biases; fused sigjoin (level 2)
    const float tl = expf(lt[0]);
#pragma unroll
    for (int n = 0; n < 2; ++n) {
        const int u = bn * 64 + wn * 32 + n * 16 + lr;
        const float bias = Wb[u] + Ub[u];
#pragma unroll
        for (int m = 0; m < 2; ++m) {
            const int rbase = bm * 128 + wm * 32 + m * 16 + (lg << 2);
#pragma unroll
            for (int i = 0; i < 4; ++i) {
                const int b = rbase + i;
                const float raw = acc[m][n][i] + bias;
                const float ps  = states[(size_t)b * NUNITS + u];
                const float d   = raw - ps;
                const float* s  = sigs + (size_t)b * KSIG + u * 6;
                const float s0 = s[0], s1 = s[1], s2 = s[2], s3 = s[3], s4 = s[4], s5 = s[5];
                float* o = out + (size_t)b * OUTW + u * 6;
                o[0] = s0 + d;
                o[1] = s1 + tl;
                o[2] = s2 + 0.5f * d * d   + s0 * d;
                o[3] = s3 + 0.5f * d * tl  + s0 * tl;
                o[4] = s4 + 0.5f * tl * d  + s1 * d;
                o[5] = s5 + 0.5f * tl * tl + s1 * tl;
                out[(size_t)b * OUTW + KSIG + u] = raw;
            }
        }
    }
#undef STAGE
}

// ---------------- fallback (validated round-3 kernel) ----------------
__global__ __launch_bounds__(1024, 4)
void rsig_fused_fb(const float* __restrict__ x,
                   const float* __restrict__ sigs,
                   const float* __restrict__ states,
                   const float* __restrict__ Ww,
                   const float* __restrict__ Wb,
                   const float* __restrict__ Uw,
                   const float* __restrict__ Ub,
                   const float* __restrict__ lt,
                   float* __restrict__ out)
{
    __shared__ unsigned short lA[2][128 * 64];
    __shared__ unsigned short lB[2][128 * 64];

    const int t = threadIdx.x;
    const int p   = blockIdx.x;
    const int lid = (p & 7) * 32 + (p >> 3);
    const int bm  = lid >> 3;
    const int bn  = lid & 7;

    const int lane = t & 63;
    const int w    = t >> 6;
    const int wm   = w >> 2;
    const int wn   = w & 3;
    const int lr   = lane & 15;
    const int lg   = lane >> 4;

    const int srow = t >> 4;
    const int sc4  = t & 15;

    f32x4 acc[2][2];
#pragma unroll
    for (int m = 0; m < 2; ++m)
#pragma unroll
        for (int n = 0; n < 2; ++n)
            acc[m][n] = (f32x4)0.f;

    float4 ra[2], rb[2];

#define LOAD_REGS(KT)                                                                   \
    {                                                                                   \
        const int kt_ = (KT);                                                           \
        const float* abase; int astr, koff;                                             \
        if (kt_ < 8)        { abase = x;      astr = INSIZE; koff = kt_ * 64; }         \
        else if (kt_ < 104) { abase = sigs;   astr = KSIG;   koff = kt_ * 64 - 512; }   \
        else                { abase = states; astr = NUNITS; koff = kt_ * 64 - 6656; }  \
        const float* bbase; int bstr, koffb;                                            \
        if (kt_ < 8)        { bbase = Ww; bstr = INSIZE; koffb = kt_ * 64; }            \
        else                { bbase = Uw; bstr = SAVED;  koffb = kt_ * 64 - 512; }      \
        _Pragma("unroll")                                                               \
        for (int j = 0; j < 2; ++j)                                                     \
            ra[j] = *(const float4*)(abase + (size_t)(bm * 128 + srow + j * 64) * astr + koff + sc4 * 4); \
        _Pragma("unroll")                                                               \
        for (int j = 0; j < 2; ++j)                                                     \
            rb[j] = *(const float4*)(bbase + (size_t)(bn * 128 + srow + j * 64) * bstr + koffb + sc4 * 4); \
    }

#define CVT_STORE(BUF)                                                                  \
    {                                                                                   \
        _Pragma("unroll")                                                               \
        for (int j = 0; j < 2; ++j) {                                                   \
            const int rr = srow + j * 64;                                               \
            ushort4 h;                                                                  \
            h.x = f2bf(ra[j].x); h.y = f2bf(ra[j].y);                                   \
            h.z = f2bf(ra[j].z); h.w = f2bf(ra[j].w);                                   \
            *(ushort4*)&lA[BUF][swz(rr, sc4 * 8)] = h;                                  \
        }                                                                               \
        _Pragma("unroll")                                                               \
        for (int j = 0; j < 2; ++j) {                                                   \
            const int rr = srow + j * 64;                                               \
            ushort4 h;                                                                  \
            h.x = f2bf(rb[j].x); h.y = f2bf(rb[j].y);                                   \
            h.z = f2bf(rb[j].z); h.w = f2bf(rb[j].w);                                   \
            *(ushort4*)&lB[BUF][swz(rr, sc4 * 8)] = h;                                  \
        }                                                                               \
    }

    LOAD_REGS(0);
    CVT_STORE(0);
    __syncthreads();

    int c = 0;
    for (int kt = 0; kt < KTOT / 64; ++kt) {
        if (kt + 1 < KTOT / 64) LOAD_REGS(kt + 1);

#pragma unroll
        for (int ks = 0; ks < 2; ++ks) {
            bf16x8 af[2], bfr[2];
#pragma unroll
            for (int m = 0; m < 2; ++m)
                af[m] = *(const bf16x8*)&lA[c][swz(wm * 32 + m * 16 + lr, ks * 64 + lg * 16)];
#pragma unroll
            for (int n = 0; n < 2; ++n)
                bfr[n] = *(const bf16x8*)&lB[c][swz(wn * 32 + n * 16 + lr, ks * 64 + lg * 16)];
#pragma unroll
            for (int m = 0; m < 2; ++m)
#pragma unroll
                for (int n = 0; n < 2; ++n)
                    acc[m][n] = __builtin_amdgcn_mfma_f32_16x16x32_bf16(af[m], bfr[n], acc[m][n], 0, 0, 0);
        }

        if (kt + 1 < KTOT / 64) CVT_STORE(c ^ 1);
        __syncthreads();
        c ^= 1;
    }

    const float tl = expf(lt[0]);
#pragma unroll
    for (int n = 0; n < 2; ++n) {
        const int u = bn * 128 + wn * 32 + n * 16 + lr;
        const float bias = Wb[u] + Ub[u];
#pragma unroll
        for (int m = 0; m < 2; ++m) {
            const int rbase = bm * 128 + wm * 32 + m * 16 + (lg << 2);
#pragma unroll
            for (int i = 0; i < 4; ++i) {
                const int b = rbase + i;
                const float raw = acc[m][n][i] + bias;
                const float ps  = states[(size_t)b * NUNITS + u];
                const float d   = raw - ps;
                const float* s  = sigs + (size_t)b * KSIG + u * 6;
                const float s0 = s[0], s1 = s[1], s2 = s[2], s3 = s[3], s4 = s[4], s5 = s[5];
                float* o = out + (size_t)b * OUTW + u * 6;
                o[0] = s0 + d;
                o[1] = s1 + tl;
                o[2] = s2 + 0.5f * d * d   + s0 * d;
                o[3] = s3 + 0.5f * d * tl  + s0 * tl;
                o[4] = s4 + 0.5f * tl * d  + s1 * d;
                o[5] = s5 + 0.5f * tl * tl + s1 * tl;
                out[(size_t)b * OUTW + KSIG + u] = raw;
            }
        }
    }
#undef LOAD_REGS
#undef CVT_STORE
}

extern "C" void kernel_launch(void* const* d_in, const int* in_sizes, int n_in,
                              void* d_out, int out_size, void* d_ws, size_t ws_size,
                              hipStream_t stream) {
    const float* x      = (const float*)d_in[0];
    const float* sigs   = (const float*)d_in[1];
    const float* states = (const float*)d_in[2];
    const float* Ww     = (const float*)d_in[3];
    const float* Wb     = (const float*)d_in[4];
    const float* Uw     = (const float*)d_in[5];
    const float* Ub     = (const float*)d_in[6];
    const float* lt     = (const float*)d_in[7];
    float* out = (float*)d_out;

    if (ws_size >= (size_t)WS_BYTES) {
        unsigned short* ws = (unsigned short*)d_ws;
        hipLaunchKernelGGL(prepack, dim3(2048), dim3(256), 0, stream,
                           x, sigs, states, Ww, Uw, ws);
        hipLaunchKernelGGL(rsig_gemm, dim3(512), dim3(512), 0, stream,
                           ws, sigs, states, Wb, Ub, lt, out);
    } else {
        hipLaunchKernelGGL(rsig_fused_fb, dim3(256), dim3(1024), 0, stream,
                           x, sigs, states, Ww, Wb, Uw, Ub, lt, out);
    }
}